// Round 8
// baseline (302.955 us; speedup 1.0000x reference)
//
#include <hip/hip_runtime.h>

#define NCTX 4096
#define DMODEL 2048
#define DHEAD 128

typedef short s16x8 __attribute__((ext_vector_type(8)));
typedef float f32x4 __attribute__((ext_vector_type(4)));
typedef unsigned short u16;

__device__ __forceinline__ u16 f2bf(float f) {
  union { float f; unsigned u; } v; v.f = f;
  unsigned u = v.u;
  return (u16)((u + 0x7FFFu + ((u >> 16) & 1u)) >> 16);
}
__device__ __forceinline__ float bf2f(u16 h) {
  union { unsigned u; float f; } v; v.u = ((unsigned)h) << 16; return v.f;
}

__device__ __forceinline__ void gl_lds16(const void* g, void* l) {
  __builtin_amdgcn_global_load_lds((const __attribute__((address_space(1))) void*)g,
                                   (__attribute__((address_space(3))) void*)l, 16, 0, 0);
}

__device__ __forceinline__ void split4(float4 v, ushort4& h, ushort4& l) {
  h.x = f2bf(v.x); l.x = f2bf(v.x - bf2f(h.x));
  h.y = f2bf(v.y); l.y = f2bf(v.y - bf2f(h.y));
  h.z = f2bf(v.z); l.z = f2bf(v.z - bf2f(h.z));
  h.w = f2bf(v.w); l.w = f2bf(v.w - bf2f(h.w));
}

// ---------------- fused prep v2: x split+transpose (x read ONCE) | W splits | W2 cast --
// block ranges: [0,2048) x 64x64 tiles -> xh,xl,XT; [2048,2304) Wq; [2304,2560) Wk;
//               [2560,6656) W2 cast.
__global__ __launch_bounds__(256) void prep_all(const float* __restrict__ x,
                                                const float* __restrict__ Wq,
                                                const float* __restrict__ Wk,
                                                const float* __restrict__ W2,
                                                u16* __restrict__ xh, u16* __restrict__ xl,
                                                u16* __restrict__ Wh, u16* __restrict__ Wl,
                                                u16* __restrict__ W2b, u16* __restrict__ XT) {
  __shared__ float tile[64][65];
  int b = blockIdx.x;
  int t = threadIdx.x;
  if (b < 2048) {                      // x tile: split + transpose
    int mb = (b >> 5) * 64, db = (b & 31) * 64;
    int tx = t & 15, ty = t >> 4;      // tx: float4 col, ty: row 0..15
#pragma unroll
    for (int rr = 0; rr < 4; ++rr) {
      int row = rr * 16 + ty;
      float4 v = *(const float4*)(x + (size_t)(mb + row) * DMODEL + db + tx * 4);
      ushort4 h, l; split4(v, h, l);
      size_t gi = ((size_t)(mb + row) * DMODEL + db) / 4 + tx;
      ((ushort4*)xh)[gi] = h; ((ushort4*)xl)[gi] = l;
      tile[row][tx * 4 + 0] = v.x; tile[row][tx * 4 + 1] = v.y;
      tile[row][tx * 4 + 2] = v.z; tile[row][tx * 4 + 3] = v.w;
    }
    __syncthreads();
#pragma unroll
    for (int rr = 0; rr < 4; ++rr) {
      int r = (t >> 4) * 4 + rr;       // d-local
      int c0 = (t & 15) * 4;           // m-local
      ushort4 o;
      o.x = f2bf(tile[c0 + 0][r]); o.y = f2bf(tile[c0 + 1][r]);
      o.z = f2bf(tile[c0 + 2][r]); o.w = f2bf(tile[c0 + 3][r]);
      *(ushort4*)(XT + (size_t)(db + r) * NCTX + mb + c0) = o;
    }
  } else if (b < 2560) {               // split Wq / Wk: 256 blocks each
    int wk = (b >= 2304);
    int i = (b - (wk ? 2304 : 2048)) * 256 + t;
    const float* W = wk ? Wk : Wq;
    size_t off = wk ? ((size_t)DHEAD * DMODEL / 4) : 0;
    float4 v = ((const float4*)W)[i];
    ushort4 h, l; split4(v, h, l);
    ((ushort4*)Wh)[off + i] = h; ((ushort4*)Wl)[off + i] = l;
  } else {                             // cast W2: 1M float4
    int i = (b - 2560) * 256 + t;
    float4 v = ((const float4*)W2)[i];
    ushort4 o;
    o.x = f2bf(v.x); o.y = f2bf(v.y); o.z = f2bf(v.z); o.w = f2bf(v.w);
    ((ushort4*)W2b)[i] = o;
  }
}

// ---------------- 8-way split-K reduce -> (hi, lo) bf16 split ----------------
__global__ __launch_bounds__(256) void reduce8_split(const float* __restrict__ P,
                                                     u16* __restrict__ hi,
                                                     u16* __restrict__ lo, int n4) {
  int i = blockIdx.x * 256 + threadIdx.x;
  if (i >= n4) return;
  float4 s = ((const float4*)P)[i];
#pragma unroll
  for (int z = 1; z < 8; ++z) {
    float4 v = ((const float4*)P)[(size_t)z * n4 + i];
    s.x += v.x; s.y += v.y; s.z += v.z; s.w += v.w;
  }
  ushort4 h, l; split4(s, h, l);
  ((ushort4*)hi)[i] = h;
  ((ushort4*)lo)[i] = l;
}

// ---------------- 2-way causal split-K reduce -> bf16 cast ----------------
// P1 covers k >= 2048: contributes only for rows >= 2048 (float4 idx >= rowsplit4).
__global__ __launch_bounds__(256) void reduce2_cast(const float* __restrict__ P0,
                                                    const float* __restrict__ P1,
                                                    u16* __restrict__ out,
                                                    int n4, int rowsplit4) {
  int i = blockIdx.x * 256 + threadIdx.x;
  if (i >= n4) return;
  float4 s = ((const float4*)P0)[i];
  if (i >= rowsplit4) {
    float4 v = ((const float4*)P1)[i];
    s.x += v.x; s.y += v.y; s.z += v.z; s.w += v.w;
  }
  ushort4 o;
  o.x = f2bf(s.x); o.y = f2bf(s.y); o.z = f2bf(s.z); o.w = f2bf(s.w);
  ((ushort4*)out)[i] = o;
}

// ---------------- 2-way split-K reduce -> fp32 ----------------
__global__ __launch_bounds__(256) void reduce2_f32(const float* __restrict__ P0,
                                                   const float* __restrict__ P1,
                                                   float* __restrict__ out, int n4) {
  int i = blockIdx.x * 256 + threadIdx.x;
  if (i >= n4) return;
  float4 a = ((const float4*)P0)[i];
  float4 b = ((const float4*)P1)[i];
  a.x += b.x; a.y += b.y; a.z += b.z; a.w += b.w;
  ((float4*)out)[i] = a;
}

// ---------------- row softmax (fp32) -> bf16 attn, one expf pass ----------------
__global__ __launch_bounds__(256) void softmax_rows(const float* __restrict__ S,
                                                    u16* __restrict__ P) {
  int i = blockIdx.x;
  int t = threadIdx.x;
  __shared__ float rowbuf[NCTX];
  __shared__ float red[4];
  __shared__ float red2[4];
  const float* srow = S + (size_t)i * NCTX;
  int len = i + 1;
  int jmax = ((i >> 7) + 1) << 7;  // causal gemm reads j < 128*(bm+1)
  float mx = -3.0e38f;
  for (int j = t; j < len; j += 256) {
    float v = srow[j];
    rowbuf[j] = v;
    mx = fmaxf(mx, v);
  }
#pragma unroll
  for (int o = 32; o > 0; o >>= 1) mx = fmaxf(mx, __shfl_xor(mx, o, 64));
  if ((t & 63) == 0) red[t >> 6] = mx;
  __syncthreads();
  mx = fmaxf(fmaxf(red[0], red[1]), fmaxf(red[2], red[3]));
  float sum = 0.f;
  for (int j = t; j < len; j += 256) {
    float e = __expf(rowbuf[j] - mx);
    rowbuf[j] = e;
    sum += e;
  }
#pragma unroll
  for (int o = 32; o > 0; o >>= 1) sum += __shfl_xor(sum, o, 64);
  if ((t & 63) == 0) red2[t >> 6] = sum;
  __syncthreads();
  float inv = 1.0f / (red2[0] + red2[1] + red2[2] + red2[3]);
  u16* prow = P + (size_t)i * NCTX;
  for (int j = t; j < jmax; j += 256) {
    float v = (j < len) ? rowbuf[j] * inv : 0.0f;
    prow[j] = f2bf(v);
  }
}

// ---------------- bf16 MFMA GEMM, B^T, 128x64 tile, BK=64, XOR swizzle ------------
// Wave tile 64x32 (acc 32 AGPRs). LDS 24 KB; __launch_bounds__(256,6) -> 6 blocks/CU
// = 24 waves/CU. split-K: chunk kc -> plain fp32 stores at C + kc*M*N.
// causal: K clipped to (bm+1)*128 (bm indexes 128-row M tiles).
__global__ __launch_bounds__(256, 6) void gemm_bt_p(const u16* __restrict__ A,
                                                    const u16* __restrict__ B,
                                                    float* __restrict__ C,
                                                    int M, int N, int K, int KC, int causal) {
  int bm = gridDim.x - 1 - blockIdx.x, bn = blockIdx.y, kc = blockIdx.z;
  int kEnd = K;
  if (causal) { int ke = (bm + 1) * 128; if (ke < kEnd) kEnd = ke; }
  int kStart = kc * KC;
  if (kStart >= kEnd) return;
  int kStop = kStart + KC < kEnd ? kStart + KC : kEnd;
  __shared__ __align__(16) u16 As[128 * 64];
  __shared__ __align__(16) u16 Bs[64 * 64];
  int t = threadIdx.x;
  int lane = t & 63, w = t >> 6;
  int m0 = bm * 128, n0 = bn * 64;
  int wm = (w >> 1) * 64, wn = (w & 1) * 32;
  int mfrag = lane & 15, quad = lane >> 4;
  int srow = t >> 3, schunk = t & 7;
  int rsw = mfrag & 7;
  f32x4 acc[4][2] = {};
  for (int kt = kStart; kt < kStop; kt += 64) {
#pragma unroll
    for (int p = 0; p < 4; ++p) {
      int row = p * 32 + srow;
      int gsc = schunk ^ (row & 7);
      gl_lds16(A + (size_t)(m0 + row) * K + kt + gsc * 8, As + (size_t)(p * 256 + t) * 8);
    }
#pragma unroll
    for (int p = 0; p < 2; ++p) {
      int row = p * 32 + srow;
      int gsc = schunk ^ (row & 7);
      gl_lds16(B + (size_t)(n0 + row) * K + kt + gsc * 8, Bs + (size_t)(p * 256 + t) * 8);
    }
    __syncthreads();
#pragma unroll
    for (int ks = 0; ks < 2; ++ks) {
      int c0 = ((ks * 4 + quad) ^ rsw) * 8;
      s16x8 af[4], bfr[2];
#pragma unroll
      for (int i = 0; i < 4; ++i)
        af[i] = *(const s16x8*)(As + (wm + i * 16 + mfrag) * 64 + c0);
#pragma unroll
      for (int j = 0; j < 2; ++j)
        bfr[j] = *(const s16x8*)(Bs + (wn + j * 16 + mfrag) * 64 + c0);
#pragma unroll
      for (int i = 0; i < 4; ++i)
#pragma unroll
        for (int j = 0; j < 2; ++j)
          acc[i][j] = __builtin_amdgcn_mfma_f32_16x16x32_bf16(af[i], bfr[j], acc[i][j], 0, 0, 0);
    }
    __syncthreads();
  }
  float* Cc = C + (size_t)kc * M * N;
#pragma unroll
  for (int i = 0; i < 4; ++i)
#pragma unroll
    for (int j = 0; j < 2; ++j)
#pragma unroll
      for (int rr = 0; rr < 4; ++rr) {
        int row = m0 + wm + i * 16 + quad * 4 + rr;
        int col = n0 + wn + j * 16 + mfrag;
        Cc[(size_t)row * N + col] = acc[i][j][rr];
      }
}

// ---------------- bf16x3 split-precision MFMA GEMM, B^T, split-K partials --------
__global__ __launch_bounds__(256, 3) void gemm_bt3_p(const u16* __restrict__ Ah,
                                                     const u16* __restrict__ Al,
                                                     const u16* __restrict__ Bh,
                                                     const u16* __restrict__ Bl,
                                                     float* __restrict__ C,
                                                     int lda, int ldb, int ldc,
                                                     int K, int KC, size_t chunkStride,
                                                     int causal) {
  int bm = gridDim.x - 1 - blockIdx.x, bn = blockIdx.y, kc = blockIdx.z;
  if (causal && bn > bm) return;
  int kStart = kc * KC;
  if (kStart >= K) return;
  int kStop = kStart + KC < K ? kStart + KC : K;
  __shared__ __align__(16) u16 Ash[128 * 32];
  __shared__ __align__(16) u16 Asl[128 * 32];
  __shared__ __align__(16) u16 Bsh[128 * 32];
  __shared__ __align__(16) u16 Bsl[128 * 32];
  int t = threadIdx.x;
  int lane = t & 63, w = t >> 6;
  int m0 = bm * 128, n0 = bn * 128;
  int wm = (w >> 1) * 64, wn = (w & 1) * 64;
  int mfrag = lane & 15, quad = lane >> 4;
  int srow = t >> 2, schunk = t & 3;
  float* Cc = C + (size_t)kc * chunkStride;
  f32x4 acc[4][4] = {};
  for (int kt = kStart; kt < kStop; kt += 32) {
#pragma unroll
    for (int p = 0; p < 2; ++p) {
      int row = p * 64 + srow;
      size_t aoff = (size_t)(m0 + row) * lda + kt + schunk * 8;
      size_t boff = (size_t)(n0 + row) * ldb + kt + schunk * 8;
      size_t loff = (size_t)(p * 256 + t) * 8;
      gl_lds16(Ah + aoff, Ash + loff);
      gl_lds16(Al + aoff, Asl + loff);
      gl_lds16(Bh + boff, Bsh + loff);
      gl_lds16(Bl + boff, Bsl + loff);
    }
    __syncthreads();
    s16x8 a0[4], a1[4], b0[4];
#pragma unroll
    for (int i = 0; i < 4; ++i)
      a0[i] = *(const s16x8*)(Ash + (wm + i * 16 + mfrag) * 32 + quad * 8);
#pragma unroll
    for (int j = 0; j < 4; ++j)
      b0[j] = *(const s16x8*)(Bsh + (wn + j * 16 + mfrag) * 32 + quad * 8);
#pragma unroll
    for (int i = 0; i < 4; ++i)
#pragma unroll
      for (int j = 0; j < 4; ++j)
        acc[i][j] = __builtin_amdgcn_mfma_f32_16x16x32_bf16(a0[i], b0[j], acc[i][j], 0, 0, 0);
#pragma unroll
    for (int i = 0; i < 4; ++i)
      a1[i] = *(const s16x8*)(Asl + (wm + i * 16 + mfrag) * 32 + quad * 8);
#pragma unroll
    for (int i = 0; i < 4; ++i)
#pragma unroll
      for (int j = 0; j < 4; ++j)
        acc[i][j] = __builtin_amdgcn_mfma_f32_16x16x32_bf16(a1[i], b0[j], acc[i][j], 0, 0, 0);
#pragma unroll
    for (int j = 0; j < 4; ++j)
      b0[j] = *(const s16x8*)(Bsl + (wn + j * 16 + mfrag) * 32 + quad * 8);
#pragma unroll
    for (int i = 0; i < 4; ++i)
#pragma unroll
      for (int j = 0; j < 4; ++j)
        acc[i][j] = __builtin_amdgcn_mfma_f32_16x16x32_bf16(a0[i], b0[j], acc[i][j], 0, 0, 0);
    __syncthreads();
  }
#pragma unroll
  for (int i = 0; i < 4; ++i)
#pragma unroll
    for (int j = 0; j < 4; ++j)
#pragma unroll
      for (int rr = 0; rr < 4; ++rr) {
        int row = m0 + wm + i * 16 + quad * 4 + rr;
        int col = n0 + wn + j * 16 + mfrag;
        Cc[(size_t)row * ldc + col] = acc[i][j][rr];
      }
}

extern "C" void kernel_launch(void* const* d_in, const int* in_sizes, int n_in,
                              void* d_out, int out_size, void* d_ws, size_t ws_size,
                              hipStream_t stream) {
  const float* x  = (const float*)d_in[0];
  const float* Wk = (const float*)d_in[1];
  const float* Wq = (const float*)d_in[2];
  const float* W2 = (const float*)d_in[3];

  char* ws = (char*)d_ws;
  const size_t MB = 1024 * 1024;
  // persistent region [0, 78 MB)
  u16*   QKh  = (u16*)  (ws + 0);            //  2 MB  [4096,256] hi
  u16*   QKl  = (u16*)  (ws + 2 * MB);       //  2 MB  lo
  u16*   Wh   = (u16*)  (ws + 4 * MB);       //  1 MB  [256,2048] (Wq ; Wk) hi
  u16*   Wl   = (u16*)  (ws + 5 * MB);       //  1 MB  lo
  u16*   xT   = (u16*)  (ws + 6 * MB);       // 16 MB  [2048,4096] bf16
  u16*   W2b  = (u16*)  (ws + 22 * MB);      //  8 MB  [2048,2048] bf16
  u16*   outb = (u16*)  (ws + 30 * MB);      // 16 MB  [4096,2048] bf16
  u16*   attn = (u16*)  (ws + 46 * MB);      // 32 MB  [4096,4096] bf16
  // reusable region A [78, 142 MB) — lifetimes strictly sequential:
  u16*   xh   = (u16*)  (ws + 78 * MB);      // 16 MB  (dead after qk gemm)
  u16*   xl   = (u16*)  (ws + 94 * MB);      // 16 MB  (dead after qk gemm)
  float* QKp  = (float*)(ws + 110 * MB);     // 32 MB  8 x [4096,256] partials
  float* S    = (float*)(ws + 78 * MB);      // 64 MB  scores (after xh/xl/QKp dead)
  float* P0   = (float*)(ws + 78 * MB);      // 32 MB  split-K partial 0 (after S dead)
  float* P1   = (float*)(ws + 110 * MB);     // 32 MB  split-K partial 1

  const int XN4 = NCTX * DMODEL / 4;
  const int QKN4 = NCTX * 256 / 4;

  // fused prep v2: x split+transpose (single x read) + W splits + W2 cast
  prep_all<<<6656, 256, 0, stream>>>(x, Wq, Wk, W2, xh, xl, Wh, Wl, W2b, xT);

  // q,k = x @ [Wq;Wk]^T via bf16x3, split-K KC=256 -> 512 blocks, 8 partials
  gemm_bt3_p<<<dim3(NCTX / 128, 2, 8), 256, 0, stream>>>(
      xh, xl, Wh, Wl, QKp, DMODEL, DMODEL, 256, DMODEL, 256, (size_t)NCTX * 256, 0);
  reduce8_split<<<(QKN4 + 255) / 256, 256, 0, stream>>>(QKp, QKh, QKl, QKN4);

  // scores = q @ k^T (lower-triangular tiles), K=128: single chunk, direct store
  gemm_bt3_p<<<dim3(NCTX / 128, NCTX / 128, 1), 256, 0, stream>>>(
      QKh, QKl, QKh + DHEAD, QKl + DHEAD, S, 256, 256, NCTX, DHEAD, DHEAD, 0, 1);
  softmax_rows<<<NCTX, 256, 0, stream>>>(S, attn);

  // out = attn @ x (causal): 128x64 tiles, grid (32,32,2), KC=2048, fp32 partials
  gemm_bt_p<<<dim3(NCTX / 128, DMODEL / 64, 2), 256, 0, stream>>>(
      attn, xT, P0, NCTX, DMODEL, NCTX, 2048, 1);
  reduce2_cast<<<(XN4 + 255) / 256, 256, 0, stream>>>(P0, P1, outb, XN4,
                                                      2048 * 2048 / 4);

  // final = out @ W2^T: 128x64 tiles, grid (32,32,2), KC=1024, fp32 partials
  gemm_bt_p<<<dim3(NCTX / 128, DMODEL / 64, 2), 256, 0, stream>>>(
      outb, W2b, P0, NCTX, DMODEL, DMODEL, 1024, 0);
  reduce2_f32<<<(XN4 + 255) / 256, 256, 0, stream>>>(P0, P1, (float*)d_out, XN4);
}

// Round 9
// 290.070 us; speedup vs baseline: 1.0444x; 1.0444x over previous
//
#include <hip/hip_runtime.h>

#define NCTX 4096
#define DMODEL 2048
#define DHEAD 128

typedef short s16x8 __attribute__((ext_vector_type(8)));
typedef float f32x4 __attribute__((ext_vector_type(4)));
typedef unsigned short u16;

__device__ __forceinline__ u16 f2bf(float f) {
  union { float f; unsigned u; } v; v.f = f;
  unsigned u = v.u;
  return (u16)((u + 0x7FFFu + ((u >> 16) & 1u)) >> 16);
}
__device__ __forceinline__ float bf2f(u16 h) {
  union { unsigned u; float f; } v; v.u = ((unsigned)h) << 16; return v.f;
}

__device__ __forceinline__ void gl_lds16(const void* g, void* l) {
  __builtin_amdgcn_global_load_lds((const __attribute__((address_space(1))) void*)g,
                                   (__attribute__((address_space(3))) void*)l, 16, 0, 0);
}

__device__ __forceinline__ void split4(float4 v, ushort4& h, ushort4& l) {
  h.x = f2bf(v.x); l.x = f2bf(v.x - bf2f(h.x));
  h.y = f2bf(v.y); l.y = f2bf(v.y - bf2f(h.y));
  h.z = f2bf(v.z); l.z = f2bf(v.z - bf2f(h.z));
  h.w = f2bf(v.w); l.w = f2bf(v.w - bf2f(h.w));
}

// ---------------- fused prep v2: x split+transpose (x read ONCE) | W splits | W2 cast --
__global__ __launch_bounds__(256) void prep_all(const float* __restrict__ x,
                                                const float* __restrict__ Wq,
                                                const float* __restrict__ Wk,
                                                const float* __restrict__ W2,
                                                u16* __restrict__ xh, u16* __restrict__ xl,
                                                u16* __restrict__ Wh, u16* __restrict__ Wl,
                                                u16* __restrict__ W2b, u16* __restrict__ XT) {
  __shared__ float tile[64][65];
  int b = blockIdx.x;
  int t = threadIdx.x;
  if (b < 2048) {                      // x tile: split + transpose
    int mb = (b >> 5) * 64, db = (b & 31) * 64;
    int tx = t & 15, ty = t >> 4;
#pragma unroll
    for (int rr = 0; rr < 4; ++rr) {
      int row = rr * 16 + ty;
      float4 v = *(const float4*)(x + (size_t)(mb + row) * DMODEL + db + tx * 4);
      ushort4 h, l; split4(v, h, l);
      size_t gi = ((size_t)(mb + row) * DMODEL + db) / 4 + tx;
      ((ushort4*)xh)[gi] = h; ((ushort4*)xl)[gi] = l;
      tile[row][tx * 4 + 0] = v.x; tile[row][tx * 4 + 1] = v.y;
      tile[row][tx * 4 + 2] = v.z; tile[row][tx * 4 + 3] = v.w;
    }
    __syncthreads();
#pragma unroll
    for (int rr = 0; rr < 4; ++rr) {
      int r = (t >> 4) * 4 + rr;
      int c0 = (t & 15) * 4;
      ushort4 o;
      o.x = f2bf(tile[c0 + 0][r]); o.y = f2bf(tile[c0 + 1][r]);
      o.z = f2bf(tile[c0 + 2][r]); o.w = f2bf(tile[c0 + 3][r]);
      *(ushort4*)(XT + (size_t)(db + r) * NCTX + mb + c0) = o;
    }
  } else if (b < 2560) {               // split Wq / Wk
    int wk = (b >= 2304);
    int i = (b - (wk ? 2304 : 2048)) * 256 + t;
    const float* W = wk ? Wk : Wq;
    size_t off = wk ? ((size_t)DHEAD * DMODEL / 4) : 0;
    float4 v = ((const float4*)W)[i];
    ushort4 h, l; split4(v, h, l);
    ((ushort4*)Wh)[off + i] = h; ((ushort4*)Wl)[off + i] = l;
  } else {                             // cast W2
    int i = (b - 2560) * 256 + t;
    float4 v = ((const float4*)W2)[i];
    ushort4 o;
    o.x = f2bf(v.x); o.y = f2bf(v.y); o.z = f2bf(v.z); o.w = f2bf(v.w);
    ((ushort4*)W2b)[i] = o;
  }
}

// ---------------- 8-way split-K reduce -> (hi, lo) bf16 split ----------------
__global__ __launch_bounds__(256) void reduce8_split(const float* __restrict__ P,
                                                     u16* __restrict__ hi,
                                                     u16* __restrict__ lo, int n4) {
  int i = blockIdx.x * 256 + threadIdx.x;
  if (i >= n4) return;
  float4 s = ((const float4*)P)[i];
#pragma unroll
  for (int z = 1; z < 8; ++z) {
    float4 v = ((const float4*)P)[(size_t)z * n4 + i];
    s.x += v.x; s.y += v.y; s.z += v.z; s.w += v.w;
  }
  ushort4 h, l; split4(s, h, l);
  ((ushort4*)hi)[i] = h;
  ((ushort4*)lo)[i] = l;
}

// ---------------- balanced-causal bf16-partial reduce -> bf16 ----------------
// Chunk z valid for rows with nchunks(bm) > z, nchunks = (bm+11)/11, bm = row>>7.
__global__ __launch_bounds__(256) void reduce3b_cast(const u16* __restrict__ P,
                                                     u16* __restrict__ out, int n4) {
  int i = blockIdx.x * 256 + threadIdx.x;
  if (i >= n4) return;
  int row = i >> 9;                     // 2048 elems = 512 ushort4 per row
  int nval = ((row >> 7) + 11) / 11;
  ushort4 p = ((const ushort4*)P)[i];
  float sx = bf2f(p.x), sy = bf2f(p.y), sz = bf2f(p.z), sw = bf2f(p.w);
  for (int z = 1; z < nval; ++z) {
    ushort4 v = ((const ushort4*)P)[(size_t)z * n4 + i];
    sx += bf2f(v.x); sy += bf2f(v.y); sz += bf2f(v.z); sw += bf2f(v.w);
  }
  ushort4 o;
  o.x = f2bf(sx); o.y = f2bf(sy); o.z = f2bf(sz); o.w = f2bf(sw);
  ((ushort4*)out)[i] = o;
}

// ---------------- 2-way split-K reduce -> fp32 ----------------
__global__ __launch_bounds__(256) void reduce2_f32(const float* __restrict__ P0,
                                                   const float* __restrict__ P1,
                                                   float* __restrict__ out, int n4) {
  int i = blockIdx.x * 256 + threadIdx.x;
  if (i >= n4) return;
  float4 a = ((const float4*)P0)[i];
  float4 b = ((const float4*)P1)[i];
  a.x += b.x; a.y += b.y; a.z += b.z; a.w += b.w;
  ((float4*)out)[i] = a;
}

// ---------------- row softmax (fp32) -> bf16 attn, vectorized ----------------
__global__ __launch_bounds__(256) void softmax_rows(const float* __restrict__ S,
                                                    u16* __restrict__ P) {
  int i = blockIdx.x;
  int t = threadIdx.x;
  __shared__ float rowbuf[NCTX];
  __shared__ float red[4];
  __shared__ float red2[4];
  const float* srow = S + (size_t)i * NCTX;
  int len = i + 1;
  int jmax = ((i >> 7) + 1) << 7;  // causal gemm reads j < 128*(bm+1)
  float mx = -3.0e38f;
  for (int j = t * 4; j < len; j += 1024) {
    if (j + 4 <= len) {
      float4 v = *(const float4*)(srow + j);
      *(float4*)(rowbuf + j) = v;
      mx = fmaxf(mx, fmaxf(fmaxf(v.x, v.y), fmaxf(v.z, v.w)));
    } else {
      for (int k = j; k < len; ++k) {
        float v = srow[k];
        rowbuf[k] = v;
        mx = fmaxf(mx, v);
      }
    }
  }
#pragma unroll
  for (int o = 32; o > 0; o >>= 1) mx = fmaxf(mx, __shfl_xor(mx, o, 64));
  if ((t & 63) == 0) red[t >> 6] = mx;
  __syncthreads();
  mx = fmaxf(fmaxf(red[0], red[1]), fmaxf(red[2], red[3]));
  float sum = 0.f;
  for (int j = t; j < len; j += 256) {
    float e = __expf(rowbuf[j] - mx);
    rowbuf[j] = e;
    sum += e;
  }
#pragma unroll
  for (int o = 32; o > 0; o >>= 1) sum += __shfl_xor(sum, o, 64);
  if ((t & 63) == 0) red2[t >> 6] = sum;
  __syncthreads();
  float inv = 1.0f / (red2[0] + red2[1] + red2[2] + red2[3]);
  u16* prow = P + (size_t)i * NCTX;
  for (int j = t * 4; j < jmax; j += 1024) {
    ushort4 o;
    o.x = (j + 0 < len) ? f2bf(rowbuf[j + 0] * inv) : (u16)0;
    o.y = (j + 1 < len) ? f2bf(rowbuf[j + 1] * inv) : (u16)0;
    o.z = (j + 2 < len) ? f2bf(rowbuf[j + 2] * inv) : (u16)0;
    o.w = (j + 3 < len) ? f2bf(rowbuf[j + 3] * inv) : (u16)0;
    *(ushort4*)(prow + j) = o;
  }
}

// ---------------- bf16 MFMA GEMM, B^T, 128x128, BK=64, XOR swizzle (R6 core) ------
// Uniform split-K, fp32 partials: chunk kc -> C + kc*M*N.
__global__ __launch_bounds__(256, 4) void gemm_bt_p(const u16* __restrict__ A,
                                                    const u16* __restrict__ B,
                                                    float* __restrict__ C,
                                                    int M, int N, int K, int KC) {
  int bm = blockIdx.x, bn = blockIdx.y, kc = blockIdx.z;
  int kStart = kc * KC;
  int kStop = kStart + KC < K ? kStart + KC : K;
  __shared__ __align__(16) u16 As[128 * 64];
  __shared__ __align__(16) u16 Bs[128 * 64];
  int t = threadIdx.x;
  int lane = t & 63, w = t >> 6;
  int m0 = bm * 128, n0 = bn * 128;
  int wm = (w >> 1) * 64, wn = (w & 1) * 64;
  int mfrag = lane & 15, quad = lane >> 4;
  int srow = t >> 3, schunk = t & 7;
  int rsw = mfrag & 7;
  f32x4 acc[4][4] = {};
  for (int kt = kStart; kt < kStop; kt += 64) {
#pragma unroll
    for (int p = 0; p < 4; ++p) {
      int row = p * 32 + srow;
      int gsc = schunk ^ (row & 7);
      gl_lds16(A + (size_t)(m0 + row) * K + kt + gsc * 8, As + (size_t)(p * 256 + t) * 8);
      gl_lds16(B + (size_t)(n0 + row) * K + kt + gsc * 8, Bs + (size_t)(p * 256 + t) * 8);
    }
    __syncthreads();
#pragma unroll
    for (int ks = 0; ks < 2; ++ks) {
      int c0 = ((ks * 4 + quad) ^ rsw) * 8;
      s16x8 af[4], bfr[4];
#pragma unroll
      for (int i = 0; i < 4; ++i)
        af[i] = *(const s16x8*)(As + (wm + i * 16 + mfrag) * 64 + c0);
#pragma unroll
      for (int j = 0; j < 4; ++j)
        bfr[j] = *(const s16x8*)(Bs + (wn + j * 16 + mfrag) * 64 + c0);
#pragma unroll
      for (int i = 0; i < 4; ++i)
#pragma unroll
        for (int j = 0; j < 4; ++j)
          acc[i][j] = __builtin_amdgcn_mfma_f32_16x16x32_bf16(af[i], bfr[j], acc[i][j], 0, 0, 0);
    }
    __syncthreads();
  }
  float* Cc = C + (size_t)kc * M * N;
#pragma unroll
  for (int i = 0; i < 4; ++i)
#pragma unroll
    for (int j = 0; j < 4; ++j)
#pragma unroll
      for (int rr = 0; rr < 4; ++rr) {
        int row = m0 + wm + i * 16 + quad * 4 + rr;
        int col = n0 + wn + j * 16 + mfrag;
        Cc[(size_t)row * N + col] = acc[i][j][rr];
      }
}

// ---------------- balanced-causal bf16 MFMA GEMM (attn @ xT) ----------------------
// Same core; per-bm chain L=2(bm+1) BK=64 iters split into nchunks=(bm+11)/11 equal
// pieces (12..22 iters each); 1008 active blocks <= 1024 residency. bf16 partials.
__global__ __launch_bounds__(256, 4) void gemm_bt_c(const u16* __restrict__ A,
                                                    const u16* __restrict__ B,
                                                    u16* __restrict__ Cb,
                                                    int M, int N, int K) {
  int bm = blockIdx.x, bn = blockIdx.y, kc = blockIdx.z;
  int n = (bm + 11) / 11;
  if (kc >= n) return;
  int L = 2 * (bm + 1);                 // iters of BK=64
  int kStart = ((L * kc) / n) * 64;
  int kStop = ((L * (kc + 1)) / n) * 64;
  __shared__ __align__(16) u16 As[128 * 64];
  __shared__ __align__(16) u16 Bs[128 * 64];
  int t = threadIdx.x;
  int lane = t & 63, w = t >> 6;
  int m0 = bm * 128, n0 = bn * 128;
  int wm = (w >> 1) * 64, wn = (w & 1) * 64;
  int mfrag = lane & 15, quad = lane >> 4;
  int srow = t >> 3, schunk = t & 7;
  int rsw = mfrag & 7;
  f32x4 acc[4][4] = {};
  for (int kt = kStart; kt < kStop; kt += 64) {
#pragma unroll
    for (int p = 0; p < 4; ++p) {
      int row = p * 32 + srow;
      int gsc = schunk ^ (row & 7);
      gl_lds16(A + (size_t)(m0 + row) * K + kt + gsc * 8, As + (size_t)(p * 256 + t) * 8);
      gl_lds16(B + (size_t)(n0 + row) * K + kt + gsc * 8, Bs + (size_t)(p * 256 + t) * 8);
    }
    __syncthreads();
#pragma unroll
    for (int ks = 0; ks < 2; ++ks) {
      int c0 = ((ks * 4 + quad) ^ rsw) * 8;
      s16x8 af[4], bfr[4];
#pragma unroll
      for (int i = 0; i < 4; ++i)
        af[i] = *(const s16x8*)(As + (wm + i * 16 + mfrag) * 64 + c0);
#pragma unroll
      for (int j = 0; j < 4; ++j)
        bfr[j] = *(const s16x8*)(Bs + (wn + j * 16 + mfrag) * 64 + c0);
#pragma unroll
      for (int i = 0; i < 4; ++i)
#pragma unroll
        for (int j = 0; j < 4; ++j)
          acc[i][j] = __builtin_amdgcn_mfma_f32_16x16x32_bf16(af[i], bfr[j], acc[i][j], 0, 0, 0);
    }
    __syncthreads();
  }
  u16* Cc = Cb + (size_t)kc * M * N;
#pragma unroll
  for (int i = 0; i < 4; ++i)
#pragma unroll
    for (int j = 0; j < 4; ++j)
#pragma unroll
      for (int rr = 0; rr < 4; ++rr) {
        int row = m0 + wm + i * 16 + quad * 4 + rr;
        int col = n0 + wn + j * 16 + mfrag;
        Cc[(size_t)row * N + col] = f2bf(acc[i][j][rr]);
      }
}

// ---------------- bf16x3 split-precision MFMA GEMM, B^T, split-K partials --------
__global__ __launch_bounds__(256, 3) void gemm_bt3_p(const u16* __restrict__ Ah,
                                                     const u16* __restrict__ Al,
                                                     const u16* __restrict__ Bh,
                                                     const u16* __restrict__ Bl,
                                                     float* __restrict__ C,
                                                     int lda, int ldb, int ldc,
                                                     int K, int KC, size_t chunkStride,
                                                     int causal) {
  int bm = gridDim.x - 1 - blockIdx.x, bn = blockIdx.y, kc = blockIdx.z;
  if (causal && bn > bm) return;
  int kStart = kc * KC;
  if (kStart >= K) return;
  int kStop = kStart + KC < K ? kStart + KC : K;
  __shared__ __align__(16) u16 Ash[128 * 32];
  __shared__ __align__(16) u16 Asl[128 * 32];
  __shared__ __align__(16) u16 Bsh[128 * 32];
  __shared__ __align__(16) u16 Bsl[128 * 32];
  int t = threadIdx.x;
  int lane = t & 63, w = t >> 6;
  int m0 = bm * 128, n0 = bn * 128;
  int wm = (w >> 1) * 64, wn = (w & 1) * 64;
  int mfrag = lane & 15, quad = lane >> 4;
  int srow = t >> 2, schunk = t & 3;
  float* Cc = C + (size_t)kc * chunkStride;
  f32x4 acc[4][4] = {};
  for (int kt = kStart; kt < kStop; kt += 32) {
#pragma unroll
    for (int p = 0; p < 2; ++p) {
      int row = p * 64 + srow;
      size_t aoff = (size_t)(m0 + row) * lda + kt + schunk * 8;
      size_t boff = (size_t)(n0 + row) * ldb + kt + schunk * 8;
      size_t loff = (size_t)(p * 256 + t) * 8;
      gl_lds16(Ah + aoff, Ash + loff);
      gl_lds16(Al + aoff, Asl + loff);
      gl_lds16(Bh + boff, Bsh + loff);
      gl_lds16(Bl + boff, Bsl + loff);
    }
    __syncthreads();
    s16x8 a0[4], a1[4], b0[4];
#pragma unroll
    for (int i = 0; i < 4; ++i)
      a0[i] = *(const s16x8*)(Ash + (wm + i * 16 + mfrag) * 32 + quad * 8);
#pragma unroll
    for (int j = 0; j < 4; ++j)
      b0[j] = *(const s16x8*)(Bsh + (wn + j * 16 + mfrag) * 32 + quad * 8);
#pragma unroll
    for (int i = 0; i < 4; ++i)
#pragma unroll
      for (int j = 0; j < 4; ++j)
        acc[i][j] = __builtin_amdgcn_mfma_f32_16x16x32_bf16(a0[i], b0[j], acc[i][j], 0, 0, 0);
#pragma unroll
    for (int i = 0; i < 4; ++i)
      a1[i] = *(const s16x8*)(Asl + (wm + i * 16 + mfrag) * 32 + quad * 8);
#pragma unroll
    for (int i = 0; i < 4; ++i)
#pragma unroll
      for (int j = 0; j < 4; ++j)
        acc[i][j] = __builtin_amdgcn_mfma_f32_16x16x32_bf16(a1[i], b0[j], acc[i][j], 0, 0, 0);
#pragma unroll
    for (int j = 0; j < 4; ++j)
      b0[j] = *(const s16x8*)(Bsl + (wn + j * 16 + mfrag) * 32 + quad * 8);
#pragma unroll
    for (int i = 0; i < 4; ++i)
#pragma unroll
      for (int j = 0; j < 4; ++j)
        acc[i][j] = __builtin_amdgcn_mfma_f32_16x16x32_bf16(a0[i], b0[j], acc[i][j], 0, 0, 0);
    __syncthreads();
  }
#pragma unroll
  for (int i = 0; i < 4; ++i)
#pragma unroll
    for (int j = 0; j < 4; ++j)
#pragma unroll
      for (int rr = 0; rr < 4; ++rr) {
        int row = m0 + wm + i * 16 + quad * 4 + rr;
        int col = n0 + wn + j * 16 + mfrag;
        Cc[(size_t)row * ldc + col] = acc[i][j][rr];
      }
}

extern "C" void kernel_launch(void* const* d_in, const int* in_sizes, int n_in,
                              void* d_out, int out_size, void* d_ws, size_t ws_size,
                              hipStream_t stream) {
  const float* x  = (const float*)d_in[0];
  const float* Wk = (const float*)d_in[1];
  const float* Wq = (const float*)d_in[2];
  const float* W2 = (const float*)d_in[3];

  char* ws = (char*)d_ws;
  const size_t MB = 1024 * 1024;
  // persistent region [0, 78 MB)
  u16*   QKh  = (u16*)  (ws + 0);            //  2 MB  [4096,256] hi
  u16*   QKl  = (u16*)  (ws + 2 * MB);       //  2 MB  lo
  u16*   Wh   = (u16*)  (ws + 4 * MB);       //  1 MB  [256,2048] (Wq ; Wk) hi
  u16*   Wl   = (u16*)  (ws + 5 * MB);       //  1 MB  lo
  u16*   xT   = (u16*)  (ws + 6 * MB);       // 16 MB  [2048,4096] bf16
  u16*   W2b  = (u16*)  (ws + 22 * MB);      //  8 MB  [2048,2048] bf16
  u16*   outb = (u16*)  (ws + 30 * MB);      // 16 MB  [4096,2048] bf16
  u16*   attn = (u16*)  (ws + 46 * MB);      // 32 MB  [4096,4096] bf16
  // reusable region A [78, 142 MB) — lifetimes strictly sequential:
  u16*   xh   = (u16*)  (ws + 78 * MB);      // 16 MB  (dead after qk gemm)
  u16*   xl   = (u16*)  (ws + 94 * MB);      // 16 MB  (dead after qk gemm)
  float* QKp  = (float*)(ws + 110 * MB);     // 32 MB  8 x [4096,256] partials
  float* S    = (float*)(ws + 78 * MB);      // 64 MB  scores (after xh/xl/QKp dead)
  u16*   Pb   = (u16*)  (ws + 78 * MB);      // 48 MB  3 x bf16 partials (after S dead)
  float* P0   = (float*)(ws + 78 * MB);      // 32 MB  final partial 0 (after Pb dead)
  float* P1   = (float*)(ws + 110 * MB);     // 32 MB  final partial 1

  const int XN4 = NCTX * DMODEL / 4;
  const int QKN4 = NCTX * 256 / 4;

  // fused prep v2: x split+transpose (single x read) + W splits + W2 cast
  prep_all<<<6656, 256, 0, stream>>>(x, Wq, Wk, W2, xh, xl, Wh, Wl, W2b, xT);

  // q,k = x @ [Wq;Wk]^T via bf16x3, split-K KC=256 -> 512 blocks, 8 partials
  gemm_bt3_p<<<dim3(NCTX / 128, 2, 8), 256, 0, stream>>>(
      xh, xl, Wh, Wl, QKp, DMODEL, DMODEL, 256, DMODEL, 256, (size_t)NCTX * 256, 0);
  reduce8_split<<<(QKN4 + 255) / 256, 256, 0, stream>>>(QKp, QKh, QKl, QKN4);

  // scores = q @ k^T (lower-triangular tiles), K=128: single chunk, direct store
  gemm_bt3_p<<<dim3(NCTX / 128, NCTX / 128, 1), 256, 0, stream>>>(
      QKh, QKl, QKh + DHEAD, QKl + DHEAD, S, 256, 256, NCTX, DHEAD, DHEAD, 0, 1);
  softmax_rows<<<NCTX, 256, 0, stream>>>(S, attn);

  // out = attn @ x (causal): balanced split (12..22-iter chains, 1008 active blocks),
  // bf16 partials
  gemm_bt_c<<<dim3(NCTX / 128, DMODEL / 128, 3), 256, 0, stream>>>(
      attn, xT, Pb, NCTX, DMODEL, NCTX);
  reduce3b_cast<<<(XN4 + 255) / 256, 256, 0, stream>>>(Pb, outb, XN4);

  // final = out @ W2^T: uniform split-K z=2, fp32 partials
  gemm_bt_p<<<dim3(NCTX / 128, DMODEL / 128, 2), 256, 0, stream>>>(
      outb, W2b, P0, NCTX, DMODEL, DMODEL, 1024);
  reduce2_f32<<<(XN4 + 255) / 256, 256, 0, stream>>>(P0, P1, (float*)d_out, XN4);
}

// Round 10
// 277.936 us; speedup vs baseline: 1.0900x; 1.0437x over previous
//
#include <hip/hip_runtime.h>

#define NCTX 4096
#define DMODEL 2048
#define DHEAD 128

typedef short s16x8 __attribute__((ext_vector_type(8)));
typedef float f32x4 __attribute__((ext_vector_type(4)));
typedef unsigned short u16;

__device__ __forceinline__ u16 f2bf(float f) {
  union { float f; unsigned u; } v; v.f = f;
  unsigned u = v.u;
  return (u16)((u + 0x7FFFu + ((u >> 16) & 1u)) >> 16);
}
__device__ __forceinline__ float bf2f(u16 h) {
  union { unsigned u; float f; } v; v.u = ((unsigned)h) << 16; return v.f;
}

__device__ __forceinline__ void gl_lds16(const void* g, void* l) {
  __builtin_amdgcn_global_load_lds((const __attribute__((address_space(1))) void*)g,
                                   (__attribute__((address_space(3))) void*)l, 16, 0, 0);
}

__device__ __forceinline__ void split4(float4 v, ushort4& h, ushort4& l) {
  h.x = f2bf(v.x); l.x = f2bf(v.x - bf2f(h.x));
  h.y = f2bf(v.y); l.y = f2bf(v.y - bf2f(h.y));
  h.z = f2bf(v.z); l.z = f2bf(v.z - bf2f(h.z));
  h.w = f2bf(v.w); l.w = f2bf(v.w - bf2f(h.w));
}

// ---------------- fused prep v2: x split+transpose (x read ONCE) | W splits | W2 cast --
__global__ __launch_bounds__(256) void prep_all(const float* __restrict__ x,
                                                const float* __restrict__ Wq,
                                                const float* __restrict__ Wk,
                                                const float* __restrict__ W2,
                                                u16* __restrict__ xh, u16* __restrict__ xl,
                                                u16* __restrict__ Wh, u16* __restrict__ Wl,
                                                u16* __restrict__ W2b, u16* __restrict__ XT) {
  __shared__ float tile[64][65];
  int b = blockIdx.x;
  int t = threadIdx.x;
  if (b < 2048) {                      // x tile: split + transpose
    int mb = (b >> 5) * 64, db = (b & 31) * 64;
    int tx = t & 15, ty = t >> 4;
#pragma unroll
    for (int rr = 0; rr < 4; ++rr) {
      int row = rr * 16 + ty;
      float4 v = *(const float4*)(x + (size_t)(mb + row) * DMODEL + db + tx * 4);
      ushort4 h, l; split4(v, h, l);
      size_t gi = ((size_t)(mb + row) * DMODEL + db) / 4 + tx;
      ((ushort4*)xh)[gi] = h; ((ushort4*)xl)[gi] = l;
      tile[row][tx * 4 + 0] = v.x; tile[row][tx * 4 + 1] = v.y;
      tile[row][tx * 4 + 2] = v.z; tile[row][tx * 4 + 3] = v.w;
    }
    __syncthreads();
#pragma unroll
    for (int rr = 0; rr < 4; ++rr) {
      int r = (t >> 4) * 4 + rr;
      int c0 = (t & 15) * 4;
      ushort4 o;
      o.x = f2bf(tile[c0 + 0][r]); o.y = f2bf(tile[c0 + 1][r]);
      o.z = f2bf(tile[c0 + 2][r]); o.w = f2bf(tile[c0 + 3][r]);
      *(ushort4*)(XT + (size_t)(db + r) * NCTX + mb + c0) = o;
    }
  } else if (b < 2560) {               // split Wq / Wk
    int wk = (b >= 2304);
    int i = (b - (wk ? 2304 : 2048)) * 256 + t;
    const float* W = wk ? Wk : Wq;
    size_t off = wk ? ((size_t)DHEAD * DMODEL / 4) : 0;
    float4 v = ((const float4*)W)[i];
    ushort4 h, l; split4(v, h, l);
    ((ushort4*)Wh)[off + i] = h; ((ushort4*)Wl)[off + i] = l;
  } else {                             // cast W2
    int i = (b - 2560) * 256 + t;
    float4 v = ((const float4*)W2)[i];
    ushort4 o;
    o.x = f2bf(v.x); o.y = f2bf(v.y); o.z = f2bf(v.z); o.w = f2bf(v.w);
    ((ushort4*)W2b)[i] = o;
  }
}

// ---------------- 8-way split-K reduce -> (hi, lo) bf16 split ----------------
__global__ __launch_bounds__(256) void reduce8_split(const float* __restrict__ P,
                                                     u16* __restrict__ hi,
                                                     u16* __restrict__ lo, int n4) {
  int i = blockIdx.x * 256 + threadIdx.x;
  if (i >= n4) return;
  float4 s = ((const float4*)P)[i];
#pragma unroll
  for (int z = 1; z < 8; ++z) {
    float4 v = ((const float4*)P)[(size_t)z * n4 + i];
    s.x += v.x; s.y += v.y; s.z += v.z; s.w += v.w;
  }
  ushort4 h, l; split4(s, h, l);
  ((ushort4*)hi)[i] = h;
  ((ushort4*)lo)[i] = l;
}

// ---------------- 2-way causal split-K reduce -> bf16 cast ----------------
// P1 covers k >= 2048: contributes only for rows >= 2048 (float4 idx >= rowsplit4).
__global__ __launch_bounds__(256) void reduce2_cast(const float* __restrict__ P0,
                                                    const float* __restrict__ P1,
                                                    u16* __restrict__ out,
                                                    int n4, int rowsplit4) {
  int i = blockIdx.x * 256 + threadIdx.x;
  if (i >= n4) return;
  float4 s = ((const float4*)P0)[i];
  if (i >= rowsplit4) {
    float4 v = ((const float4*)P1)[i];
    s.x += v.x; s.y += v.y; s.z += v.z; s.w += v.w;
  }
  ushort4 o;
  o.x = f2bf(s.x); o.y = f2bf(s.y); o.z = f2bf(s.z); o.w = f2bf(s.w);
  ((ushort4*)out)[i] = o;
}

// ---------------- 2-way split-K reduce -> fp32 ----------------
__global__ __launch_bounds__(256) void reduce2_f32(const float* __restrict__ P0,
                                                   const float* __restrict__ P1,
                                                   float* __restrict__ out, int n4) {
  int i = blockIdx.x * 256 + threadIdx.x;
  if (i >= n4) return;
  float4 a = ((const float4*)P0)[i];
  float4 b = ((const float4*)P1)[i];
  a.x += b.x; a.y += b.y; a.z += b.z; a.w += b.w;
  ((float4*)out)[i] = a;
}

// ---------------- row softmax (fp32) -> bf16 attn, vectorized ----------------
__global__ __launch_bounds__(256) void softmax_rows(const float* __restrict__ S,
                                                    u16* __restrict__ P) {
  int i = blockIdx.x;
  int t = threadIdx.x;
  __shared__ float rowbuf[NCTX];
  __shared__ float red[4];
  __shared__ float red2[4];
  const float* srow = S + (size_t)i * NCTX;
  int len = i + 1;
  int jmax = ((i >> 7) + 1) << 7;  // causal gemm reads j < 128*(bm+1)
  float mx = -3.0e38f;
  for (int j = t * 4; j < len; j += 1024) {
    if (j + 4 <= len) {
      float4 v = *(const float4*)(srow + j);
      *(float4*)(rowbuf + j) = v;
      mx = fmaxf(mx, fmaxf(fmaxf(v.x, v.y), fmaxf(v.z, v.w)));
    } else {
      for (int k = j; k < len; ++k) {
        float v = srow[k];
        rowbuf[k] = v;
        mx = fmaxf(mx, v);
      }
    }
  }
#pragma unroll
  for (int o = 32; o > 0; o >>= 1) mx = fmaxf(mx, __shfl_xor(mx, o, 64));
  if ((t & 63) == 0) red[t >> 6] = mx;
  __syncthreads();
  mx = fmaxf(fmaxf(red[0], red[1]), fmaxf(red[2], red[3]));
  float sum = 0.f;
  for (int j = t; j < len; j += 256) {
    float e = __expf(rowbuf[j] - mx);
    rowbuf[j] = e;
    sum += e;
  }
#pragma unroll
  for (int o = 32; o > 0; o >>= 1) sum += __shfl_xor(sum, o, 64);
  if ((t & 63) == 0) red2[t >> 6] = sum;
  __syncthreads();
  float inv = 1.0f / (red2[0] + red2[1] + red2[2] + red2[3]);
  u16* prow = P + (size_t)i * NCTX;
  for (int j = t * 4; j < jmax; j += 1024) {
    ushort4 o;
    o.x = (j + 0 < len) ? f2bf(rowbuf[j + 0] * inv) : (u16)0;
    o.y = (j + 1 < len) ? f2bf(rowbuf[j + 1] * inv) : (u16)0;
    o.z = (j + 2 < len) ? f2bf(rowbuf[j + 2] * inv) : (u16)0;
    o.w = (j + 3 < len) ? f2bf(rowbuf[j + 3] * inv) : (u16)0;
    *(ushort4*)(prow + j) = o;
  }
}

// ---------------- bf16 MFMA GEMM, B^T, 128x128, BK=64, XOR swizzle (R6 core) ------
// split-K -> per-chunk fp32 partials (plain stores). 4 blocks/CU. Heavy-first bm.
// causal: K clipped to (bm+1)*128.
__global__ __launch_bounds__(256, 4) void gemm_bt_p(const u16* __restrict__ A,
                                                    const u16* __restrict__ B,
                                                    float* __restrict__ C,
                                                    int M, int N, int K, int KC, int causal) {
  int bm = gridDim.x - 1 - blockIdx.x, bn = blockIdx.y, kc = blockIdx.z;
  int kEnd = K;
  if (causal) { int ke = (bm + 1) * 128; if (ke < kEnd) kEnd = ke; }
  int kStart = kc * KC;
  if (kStart >= kEnd) return;
  int kStop = kStart + KC < kEnd ? kStart + KC : kEnd;
  __shared__ __align__(16) u16 As[128 * 64];
  __shared__ __align__(16) u16 Bs[128 * 64];
  int t = threadIdx.x;
  int lane = t & 63, w = t >> 6;
  int m0 = bm * 128, n0 = bn * 128;
  int wm = (w >> 1) * 64, wn = (w & 1) * 64;
  int mfrag = lane & 15, quad = lane >> 4;
  int srow = t >> 3, schunk = t & 7;
  int rsw = mfrag & 7;
  f32x4 acc[4][4] = {};
  for (int kt = kStart; kt < kStop; kt += 64) {
#pragma unroll
    for (int p = 0; p < 4; ++p) {
      int row = p * 32 + srow;
      int gsc = schunk ^ (row & 7);
      gl_lds16(A + (size_t)(m0 + row) * K + kt + gsc * 8, As + (size_t)(p * 256 + t) * 8);
      gl_lds16(B + (size_t)(n0 + row) * K + kt + gsc * 8, Bs + (size_t)(p * 256 + t) * 8);
    }
    __syncthreads();
#pragma unroll
    for (int ks = 0; ks < 2; ++ks) {
      int c0 = ((ks * 4 + quad) ^ rsw) * 8;
      s16x8 af[4], bfr[4];
#pragma unroll
      for (int i = 0; i < 4; ++i)
        af[i] = *(const s16x8*)(As + (wm + i * 16 + mfrag) * 64 + c0);
#pragma unroll
      for (int j = 0; j < 4; ++j)
        bfr[j] = *(const s16x8*)(Bs + (wn + j * 16 + mfrag) * 64 + c0);
#pragma unroll
      for (int i = 0; i < 4; ++i)
#pragma unroll
        for (int j = 0; j < 4; ++j)
          acc[i][j] = __builtin_amdgcn_mfma_f32_16x16x32_bf16(af[i], bfr[j], acc[i][j], 0, 0, 0);
    }
    __syncthreads();
  }
  float* Cc = C + (size_t)kc * M * N;
#pragma unroll
  for (int i = 0; i < 4; ++i)
#pragma unroll
    for (int j = 0; j < 4; ++j)
#pragma unroll
      for (int rr = 0; rr < 4; ++rr) {
        int row = m0 + wm + i * 16 + quad * 4 + rr;
        int col = n0 + wn + j * 16 + mfrag;
        Cc[(size_t)row * N + col] = acc[i][j][rr];
      }
}

// ---------------- bf16x3 split-precision MFMA GEMM, B^T, BK=32, XOR swizzle -------
// Swizzle: 64 B LDS rows; global chunk schunk^((row>>1)&3) staged at linear slot ->
// fragment reads hit all 8 16B bank-groups (2-way aliasing = free).
__global__ __launch_bounds__(256, 4) void gemm_bt3_p(const u16* __restrict__ Ah,
                                                     const u16* __restrict__ Al,
                                                     const u16* __restrict__ Bh,
                                                     const u16* __restrict__ Bl,
                                                     float* __restrict__ C,
                                                     int lda, int ldb, int ldc,
                                                     int K, int KC, size_t chunkStride,
                                                     int causal) {
  int bm = gridDim.x - 1 - blockIdx.x, bn = blockIdx.y, kc = blockIdx.z;
  if (causal && bn > bm) return;
  int kStart = kc * KC;
  if (kStart >= K) return;
  int kStop = kStart + KC < K ? kStart + KC : K;
  __shared__ __align__(16) u16 Ash[128 * 32];
  __shared__ __align__(16) u16 Asl[128 * 32];
  __shared__ __align__(16) u16 Bsh[128 * 32];
  __shared__ __align__(16) u16 Bsl[128 * 32];
  int t = threadIdx.x;
  int lane = t & 63, w = t >> 6;
  int m0 = bm * 128, n0 = bn * 128;
  int wm = (w >> 1) * 64, wn = (w & 1) * 64;
  int mfrag = lane & 15, quad = lane >> 4;
  int srow = t >> 2, schunk = t & 3;
  float* Cc = C + (size_t)kc * chunkStride;
  f32x4 acc[4][4] = {};
  for (int kt = kStart; kt < kStop; kt += 32) {
#pragma unroll
    for (int p = 0; p < 2; ++p) {
      int row = p * 64 + srow;
      int gsc = schunk ^ ((row >> 1) & 3);
      size_t aoff = (size_t)(m0 + row) * lda + kt + gsc * 8;
      size_t boff = (size_t)(n0 + row) * ldb + kt + gsc * 8;
      size_t loff = (size_t)(p * 256 + t) * 8;
      gl_lds16(Ah + aoff, Ash + loff);
      gl_lds16(Al + aoff, Asl + loff);
      gl_lds16(Bh + boff, Bsh + loff);
      gl_lds16(Bl + boff, Bsl + loff);
    }
    __syncthreads();
    s16x8 a0[4], a1[4], b0[4];
#pragma unroll
    for (int i = 0; i < 4; ++i) {
      int row = wm + i * 16 + mfrag;
      a0[i] = *(const s16x8*)(Ash + row * 32 + (quad ^ ((row >> 1) & 3)) * 8);
    }
#pragma unroll
    for (int j = 0; j < 4; ++j) {
      int row = wn + j * 16 + mfrag;
      b0[j] = *(const s16x8*)(Bsh + row * 32 + (quad ^ ((row >> 1) & 3)) * 8);
    }
#pragma unroll
    for (int i = 0; i < 4; ++i)
#pragma unroll
      for (int j = 0; j < 4; ++j)
        acc[i][j] = __builtin_amdgcn_mfma_f32_16x16x32_bf16(a0[i], b0[j], acc[i][j], 0, 0, 0);
#pragma unroll
    for (int i = 0; i < 4; ++i) {
      int row = wm + i * 16 + mfrag;
      a1[i] = *(const s16x8*)(Asl + row * 32 + (quad ^ ((row >> 1) & 3)) * 8);
    }
#pragma unroll
    for (int i = 0; i < 4; ++i)
#pragma unroll
      for (int j = 0; j < 4; ++j)
        acc[i][j] = __builtin_amdgcn_mfma_f32_16x16x32_bf16(a1[i], b0[j], acc[i][j], 0, 0, 0);
#pragma unroll
    for (int j = 0; j < 4; ++j) {
      int row = wn + j * 16 + mfrag;
      b0[j] = *(const s16x8*)(Bsl + row * 32 + (quad ^ ((row >> 1) & 3)) * 8);
    }
#pragma unroll
    for (int i = 0; i < 4; ++i)
#pragma unroll
      for (int j = 0; j < 4; ++j)
        acc[i][j] = __builtin_amdgcn_mfma_f32_16x16x32_bf16(a0[i], b0[j], acc[i][j], 0, 0, 0);
    __syncthreads();
  }
#pragma unroll
  for (int i = 0; i < 4; ++i)
#pragma unroll
    for (int j = 0; j < 4; ++j)
#pragma unroll
      for (int rr = 0; rr < 4; ++rr) {
        int row = m0 + wm + i * 16 + quad * 4 + rr;
        int col = n0 + wn + j * 16 + mfrag;
        Cc[(size_t)row * ldc + col] = acc[i][j][rr];
      }
}

extern "C" void kernel_launch(void* const* d_in, const int* in_sizes, int n_in,
                              void* d_out, int out_size, void* d_ws, size_t ws_size,
                              hipStream_t stream) {
  const float* x  = (const float*)d_in[0];
  const float* Wk = (const float*)d_in[1];
  const float* Wq = (const float*)d_in[2];
  const float* W2 = (const float*)d_in[3];

  char* ws = (char*)d_ws;
  const size_t MB = 1024 * 1024;
  // persistent region [0, 78 MB)
  u16*   QKh  = (u16*)  (ws + 0);            //  2 MB  [4096,256] hi
  u16*   QKl  = (u16*)  (ws + 2 * MB);       //  2 MB  lo
  u16*   Wh   = (u16*)  (ws + 4 * MB);       //  1 MB  [256,2048] (Wq ; Wk) hi
  u16*   Wl   = (u16*)  (ws + 5 * MB);       //  1 MB  lo
  u16*   xT   = (u16*)  (ws + 6 * MB);       // 16 MB  [2048,4096] bf16
  u16*   W2b  = (u16*)  (ws + 22 * MB);      //  8 MB  [2048,2048] bf16
  u16*   outb = (u16*)  (ws + 30 * MB);      // 16 MB  [4096,2048] bf16
  u16*   attn = (u16*)  (ws + 46 * MB);      // 32 MB  [4096,4096] bf16
  // reusable region A [78, 142 MB) — lifetimes strictly sequential:
  u16*   xh   = (u16*)  (ws + 78 * MB);      // 16 MB  (dead after qk gemm)
  u16*   xl   = (u16*)  (ws + 94 * MB);      // 16 MB  (dead after qk gemm)
  float* QKp  = (float*)(ws + 110 * MB);     // 32 MB  8 x [4096,256] partials
  float* S    = (float*)(ws + 78 * MB);      // 64 MB  scores (after xh/xl/QKp dead)
  float* P0   = (float*)(ws + 78 * MB);      // 32 MB  split-K partial 0 (after S dead)
  float* P1   = (float*)(ws + 110 * MB);     // 32 MB  split-K partial 1

  const int XN4 = NCTX * DMODEL / 4;
  const int QKN4 = NCTX * 256 / 4;

  // fused prep v2: x split+transpose (single x read) + W splits + W2 cast
  prep_all<<<6656, 256, 0, stream>>>(x, Wq, Wk, W2, xh, xl, Wh, Wl, W2b, xT);

  // q,k = x @ [Wq;Wk]^T via bf16x3, split-K KC=256 -> 512 blocks, 8 partials
  gemm_bt3_p<<<dim3(NCTX / 128, 2, 8), 256, 0, stream>>>(
      xh, xl, Wh, Wl, QKp, DMODEL, DMODEL, 256, DMODEL, 256, (size_t)NCTX * 256, 0);
  reduce8_split<<<(QKN4 + 255) / 256, 256, 0, stream>>>(QKp, QKh, QKl, QKN4);

  // scores = q @ k^T (lower-triangular tiles), K=128: single chunk, direct store
  gemm_bt3_p<<<dim3(NCTX / 128, NCTX / 128, 1), 256, 0, stream>>>(
      QKh, QKl, QKh + DHEAD, QKl + DHEAD, S, 256, 256, NCTX, DHEAD, DHEAD, 0, 1);
  softmax_rows<<<NCTX, 256, 0, stream>>>(S, attn);

  // out = attn @ x (causal): R6 config — z=2, KC=2048, fp32 partials
  gemm_bt_p<<<dim3(NCTX / 128, DMODEL / 128, 2), 256, 0, stream>>>(
      attn, xT, P0, NCTX, DMODEL, NCTX, 2048, 1);
  reduce2_cast<<<(XN4 + 255) / 256, 256, 0, stream>>>(P0, P1, outb, XN4,
                                                      2048 * 2048 / 4);

  // final = out @ W2^T: z=2, KC=1024, fp32 partials
  gemm_bt_p<<<dim3(NCTX / 128, DMODEL / 128, 2), 256, 0, stream>>>(
      outb, W2b, P0, NCTX, DMODEL, DMODEL, 1024, 0);
  reduce2_f32<<<(XN4 + 255) / 256, 256, 0, stream>>>(P0, P1, (float*)d_out, XN4);
}

// Round 11
// 274.480 us; speedup vs baseline: 1.1037x; 1.0126x over previous
//
#include <hip/hip_runtime.h>

#define NCTX 4096
#define DMODEL 2048
#define DHEAD 128

typedef _Float16 f16;
typedef f16 f16x8 __attribute__((ext_vector_type(8)));
typedef float f32x4 __attribute__((ext_vector_type(4)));
typedef unsigned short u16;

__device__ __forceinline__ u16 f2h(float f) {
  union { f16 h; u16 u; } v; v.h = (f16)f; return v.u;
}
__device__ __forceinline__ float h2f(u16 u) {
  union { u16 u; f16 h; } v; v.u = u; return (float)v.h;
}

__device__ __forceinline__ void gl_lds16(const void* g, void* l) {
  __builtin_amdgcn_global_load_lds((const __attribute__((address_space(1))) void*)g,
                                   (__attribute__((address_space(3))) void*)l, 16, 0, 0);
}

// fp32 -> (hi, lo) f16 split: hi+lo represents x to ~2^-22
__device__ __forceinline__ void splitH4(float4 v, ushort4& h, ushort4& l) {
  h.x = f2h(v.x); l.x = f2h(v.x - h2f(h.x));
  h.y = f2h(v.y); l.y = f2h(v.y - h2f(h.y));
  h.z = f2h(v.z); l.z = f2h(v.z - h2f(h.z));
  h.w = f2h(v.w); l.w = f2h(v.w - h2f(h.w));
}

// ------------- fused prep: x f16-split + f16-transpose | W casts | W2 cast ----------
// [0,2048) x 64x64 tiles -> xh,xl,XT; [2048,2560) Wq|Wk cast; [2560,6656) W2 cast.
__global__ __launch_bounds__(256) void prep_all(const float* __restrict__ x,
                                                const float* __restrict__ Wq,
                                                const float* __restrict__ Wk,
                                                const float* __restrict__ W2,
                                                u16* __restrict__ xh, u16* __restrict__ xl,
                                                u16* __restrict__ Wf, u16* __restrict__ W2f,
                                                u16* __restrict__ XT) {
  __shared__ float tile[64][65];
  int b = blockIdx.x;
  int t = threadIdx.x;
  if (b < 2048) {
    int mb = (b >> 5) * 64, db = (b & 31) * 64;
    int tx = t & 15, ty = t >> 4;
#pragma unroll
    for (int rr = 0; rr < 4; ++rr) {
      int row = rr * 16 + ty;
      float4 v = *(const float4*)(x + (size_t)(mb + row) * DMODEL + db + tx * 4);
      ushort4 h, l; splitH4(v, h, l);
      size_t gi = ((size_t)(mb + row) * DMODEL + db) / 4 + tx;
      ((ushort4*)xh)[gi] = h; ((ushort4*)xl)[gi] = l;
      tile[row][tx * 4 + 0] = v.x; tile[row][tx * 4 + 1] = v.y;
      tile[row][tx * 4 + 2] = v.z; tile[row][tx * 4 + 3] = v.w;
    }
    __syncthreads();
#pragma unroll
    for (int rr = 0; rr < 4; ++rr) {
      int r = (t >> 4) * 4 + rr;
      int c0 = (t & 15) * 4;
      ushort4 o;
      o.x = f2h(tile[c0 + 0][r]); o.y = f2h(tile[c0 + 1][r]);
      o.z = f2h(tile[c0 + 2][r]); o.w = f2h(tile[c0 + 3][r]);
      *(ushort4*)(XT + (size_t)(db + r) * NCTX + mb + c0) = o;
    }
  } else if (b < 2560) {               // cast Wq | Wk (single f16)
    int wk = (b >= 2304);
    int i = (b - (wk ? 2304 : 2048)) * 256 + t;
    const float* W = wk ? Wk : Wq;
    size_t off = wk ? ((size_t)DHEAD * DMODEL / 4) : 0;
    float4 v = ((const float4*)W)[i];
    ushort4 o;
    o.x = f2h(v.x); o.y = f2h(v.y); o.z = f2h(v.z); o.w = f2h(v.w);
    ((ushort4*)Wf)[off + i] = o;
  } else {                             // cast W2
    int i = (b - 2560) * 256 + t;
    float4 v = ((const float4*)W2)[i];
    ushort4 o;
    o.x = f2h(v.x); o.y = f2h(v.y); o.z = f2h(v.z); o.w = f2h(v.w);
    ((ushort4*)W2f)[i] = o;
  }
}

// ---------------- 8-way split-K reduce -> f16 ----------------
__global__ __launch_bounds__(256) void reduce8_f16(const float* __restrict__ P,
                                                   u16* __restrict__ out, int n4) {
  int i = blockIdx.x * 256 + threadIdx.x;
  if (i >= n4) return;
  float4 s = ((const float4*)P)[i];
#pragma unroll
  for (int z = 1; z < 8; ++z) {
    float4 v = ((const float4*)P)[(size_t)z * n4 + i];
    s.x += v.x; s.y += v.y; s.z += v.z; s.w += v.w;
  }
  ushort4 o;
  o.x = f2h(s.x); o.y = f2h(s.y); o.z = f2h(s.z); o.w = f2h(s.w);
  ((ushort4*)out)[i] = o;
}

// ---------------- 2-way causal split-K reduce -> f16 ----------------
__global__ __launch_bounds__(256) void reduce2_cast(const float* __restrict__ P0,
                                                    const float* __restrict__ P1,
                                                    u16* __restrict__ out,
                                                    int n4, int rowsplit4) {
  int i = blockIdx.x * 256 + threadIdx.x;
  if (i >= n4) return;
  float4 s = ((const float4*)P0)[i];
  if (i >= rowsplit4) {
    float4 v = ((const float4*)P1)[i];
    s.x += v.x; s.y += v.y; s.z += v.z; s.w += v.w;
  }
  ushort4 o;
  o.x = f2h(s.x); o.y = f2h(s.y); o.z = f2h(s.z); o.w = f2h(s.w);
  ((ushort4*)out)[i] = o;
}

// ---------------- 2-way split-K reduce -> fp32 ----------------
__global__ __launch_bounds__(256) void reduce2_f32(const float* __restrict__ P0,
                                                   const float* __restrict__ P1,
                                                   float* __restrict__ out, int n4) {
  int i = blockIdx.x * 256 + threadIdx.x;
  if (i >= n4) return;
  float4 a = ((const float4*)P0)[i];
  float4 b = ((const float4*)P1)[i];
  a.x += b.x; a.y += b.y; a.z += b.z; a.w += b.w;
  ((float4*)out)[i] = a;
}

// ---------------- row softmax (fp32) -> f16 attn ----------------
__global__ __launch_bounds__(256) void softmax_rows(const float* __restrict__ S,
                                                    u16* __restrict__ P) {
  int i = blockIdx.x;
  int t = threadIdx.x;
  __shared__ float rowbuf[NCTX];
  __shared__ float red[4];
  __shared__ float red2[4];
  const float* srow = S + (size_t)i * NCTX;
  int len = i + 1;
  int jmax = ((i >> 7) + 1) << 7;  // causal gemm reads j < 128*(bm+1)
  float mx = -3.0e38f;
  for (int j = t * 4; j < len; j += 1024) {
    if (j + 4 <= len) {
      float4 v = *(const float4*)(srow + j);
      *(float4*)(rowbuf + j) = v;
      mx = fmaxf(mx, fmaxf(fmaxf(v.x, v.y), fmaxf(v.z, v.w)));
    } else {
      for (int k = j; k < len; ++k) {
        float v = srow[k];
        rowbuf[k] = v;
        mx = fmaxf(mx, v);
      }
    }
  }
#pragma unroll
  for (int o = 32; o > 0; o >>= 1) mx = fmaxf(mx, __shfl_xor(mx, o, 64));
  if ((t & 63) == 0) red[t >> 6] = mx;
  __syncthreads();
  mx = fmaxf(fmaxf(red[0], red[1]), fmaxf(red[2], red[3]));
  float sum = 0.f;
  for (int j = t; j < len; j += 256) {
    float e = __expf(rowbuf[j] - mx);
    rowbuf[j] = e;
    sum += e;
  }
#pragma unroll
  for (int o = 32; o > 0; o >>= 1) sum += __shfl_xor(sum, o, 64);
  if ((t & 63) == 0) red2[t >> 6] = sum;
  __syncthreads();
  float inv = 1.0f / (red2[0] + red2[1] + red2[2] + red2[3]);
  u16* prow = P + (size_t)i * NCTX;
  for (int j = t * 4; j < jmax; j += 1024) {
    ushort4 o;
    o.x = (j + 0 < len) ? f2h(rowbuf[j + 0] * inv) : (u16)0;
    o.y = (j + 1 < len) ? f2h(rowbuf[j + 1] * inv) : (u16)0;
    o.z = (j + 2 < len) ? f2h(rowbuf[j + 2] * inv) : (u16)0;
    o.w = (j + 3 < len) ? f2h(rowbuf[j + 3] * inv) : (u16)0;
    *(ushort4*)(prow + j) = o;
  }
}

// ---------------- f16 MFMA GEMM, B^T, 128x128, BK=64, XOR swizzle (R6 core) -------
// split-K -> per-chunk fp32 partials (plain stores at C + kc*chunkStride).
// causal: K clipped to (bm+1)*128.  tri: skip tiles with bn > bm (scores).
__global__ __launch_bounds__(256, 4) void gemm_f16_p(const u16* __restrict__ A,
                                                     const u16* __restrict__ B,
                                                     float* __restrict__ C,
                                                     int lda, int ldb, int ldc,
                                                     int K, int KC, size_t chunkStride,
                                                     int causal, int tri) {
  int bm = gridDim.x - 1 - blockIdx.x, bn = blockIdx.y, kc = blockIdx.z;
  if (tri && bn > bm) return;
  int kEnd = K;
  if (causal) { int ke = (bm + 1) * 128; if (ke < kEnd) kEnd = ke; }
  int kStart = kc * KC;
  if (kStart >= kEnd) return;
  int kStop = kStart + KC < kEnd ? kStart + KC : kEnd;
  __shared__ __align__(16) u16 As[128 * 64];
  __shared__ __align__(16) u16 Bs[128 * 64];
  int t = threadIdx.x;
  int lane = t & 63, w = t >> 6;
  int m0 = bm * 128, n0 = bn * 128;
  int wm = (w >> 1) * 64, wn = (w & 1) * 64;
  int mfrag = lane & 15, quad = lane >> 4;
  int srow = t >> 3, schunk = t & 7;
  int rsw = mfrag & 7;
  f32x4 acc[4][4] = {};
  for (int kt = kStart; kt < kStop; kt += 64) {
#pragma unroll
    for (int p = 0; p < 4; ++p) {
      int row = p * 32 + srow;
      int gsc = schunk ^ (row & 7);
      gl_lds16(A + (size_t)(m0 + row) * lda + kt + gsc * 8, As + (size_t)(p * 256 + t) * 8);
      gl_lds16(B + (size_t)(n0 + row) * ldb + kt + gsc * 8, Bs + (size_t)(p * 256 + t) * 8);
    }
    __syncthreads();
#pragma unroll
    for (int ks = 0; ks < 2; ++ks) {
      int c0 = ((ks * 4 + quad) ^ rsw) * 8;
      f16x8 af[4], bfr[4];
#pragma unroll
      for (int i = 0; i < 4; ++i)
        af[i] = *(const f16x8*)(As + (wm + i * 16 + mfrag) * 64 + c0);
#pragma unroll
      for (int j = 0; j < 4; ++j)
        bfr[j] = *(const f16x8*)(Bs + (wn + j * 16 + mfrag) * 64 + c0);
#pragma unroll
      for (int i = 0; i < 4; ++i)
#pragma unroll
        for (int j = 0; j < 4; ++j)
          acc[i][j] = __builtin_amdgcn_mfma_f32_16x16x32_f16(af[i], bfr[j], acc[i][j], 0, 0, 0);
    }
    __syncthreads();
  }
  float* Cc = C + (size_t)kc * chunkStride;
#pragma unroll
  for (int i = 0; i < 4; ++i)
#pragma unroll
    for (int j = 0; j < 4; ++j)
#pragma unroll
      for (int rr = 0; rr < 4; ++rr) {
        int row = m0 + wm + i * 16 + quad * 4 + rr;
        int col = n0 + wn + j * 16 + mfrag;
        Cc[(size_t)row * ldc + col] = acc[i][j][rr];
      }
}

// ---------------- f16x2 split-A MFMA GEMM (qk projection) -------------------------
// C = (Ah+Al) @ B^T, fp32-accurate in A; B single f16 (rounding ~2^-11, harmless).
// BK=64, 3 LDS buffers (48 KB), (256,3). split-K partials.
__global__ __launch_bounds__(256, 3) void gemm_f16x2_p(const u16* __restrict__ Ah,
                                                       const u16* __restrict__ Al,
                                                       const u16* __restrict__ B,
                                                       float* __restrict__ C,
                                                       int lda, int ldb, int ldc,
                                                       int K, int KC, size_t chunkStride) {
  int bm = blockIdx.x, bn = blockIdx.y, kc = blockIdx.z;
  int kStart = kc * KC;
  int kStop = kStart + KC < K ? kStart + KC : K;
  __shared__ __align__(16) u16 Ash[128 * 64];
  __shared__ __align__(16) u16 Asl[128 * 64];
  __shared__ __align__(16) u16 Bs[128 * 64];
  int t = threadIdx.x;
  int lane = t & 63, w = t >> 6;
  int m0 = bm * 128, n0 = bn * 128;
  int wm = (w >> 1) * 64, wn = (w & 1) * 64;
  int mfrag = lane & 15, quad = lane >> 4;
  int srow = t >> 3, schunk = t & 7;
  int rsw = mfrag & 7;
  f32x4 acc[4][4] = {};
  for (int kt = kStart; kt < kStop; kt += 64) {
#pragma unroll
    for (int p = 0; p < 4; ++p) {
      int row = p * 32 + srow;
      int gsc = schunk ^ (row & 7);
      size_t aoff = (size_t)(m0 + row) * lda + kt + gsc * 8;
      size_t loff = (size_t)(p * 256 + t) * 8;
      gl_lds16(Ah + aoff, Ash + loff);
      gl_lds16(Al + aoff, Asl + loff);
      gl_lds16(B + (size_t)(n0 + row) * ldb + kt + gsc * 8, Bs + loff);
    }
    __syncthreads();
#pragma unroll
    for (int ks = 0; ks < 2; ++ks) {
      int c0 = ((ks * 4 + quad) ^ rsw) * 8;
      f16x8 a0[4], bfr[4];
#pragma unroll
      for (int j = 0; j < 4; ++j)
        bfr[j] = *(const f16x8*)(Bs + (wn + j * 16 + mfrag) * 64 + c0);
#pragma unroll
      for (int i = 0; i < 4; ++i)
        a0[i] = *(const f16x8*)(Ash + (wm + i * 16 + mfrag) * 64 + c0);
#pragma unroll
      for (int i = 0; i < 4; ++i)
#pragma unroll
        for (int j = 0; j < 4; ++j)
          acc[i][j] = __builtin_amdgcn_mfma_f32_16x16x32_f16(a0[i], bfr[j], acc[i][j], 0, 0, 0);
#pragma unroll
      for (int i = 0; i < 4; ++i)
        a0[i] = *(const f16x8*)(Asl + (wm + i * 16 + mfrag) * 64 + c0);
#pragma unroll
      for (int i = 0; i < 4; ++i)
#pragma unroll
        for (int j = 0; j < 4; ++j)
          acc[i][j] = __builtin_amdgcn_mfma_f32_16x16x32_f16(a0[i], bfr[j], acc[i][j], 0, 0, 0);
    }
    __syncthreads();
  }
  float* Cc = C + (size_t)kc * chunkStride;
#pragma unroll
  for (int i = 0; i < 4; ++i)
#pragma unroll
    for (int j = 0; j < 4; ++j)
#pragma unroll
      for (int rr = 0; rr < 4; ++rr) {
        int row = m0 + wm + i * 16 + quad * 4 + rr;
        int col = n0 + wn + j * 16 + mfrag;
        Cc[(size_t)row * ldc + col] = acc[i][j][rr];
      }
}

extern "C" void kernel_launch(void* const* d_in, const int* in_sizes, int n_in,
                              void* d_out, int out_size, void* d_ws, size_t ws_size,
                              hipStream_t stream) {
  const float* x  = (const float*)d_in[0];
  const float* Wk = (const float*)d_in[1];
  const float* Wq = (const float*)d_in[2];
  const float* W2 = (const float*)d_in[3];

  char* ws = (char*)d_ws;
  const size_t MB = 1024 * 1024;
  // persistent region [0, 75 MB)
  u16*   QKf  = (u16*)  (ws + 0);            //  2 MB  [4096,256] f16 (q | k)
  u16*   Wf   = (u16*)  (ws + 2 * MB);       //  1 MB  [256,2048] (Wq ; Wk) f16
  u16*   xT   = (u16*)  (ws + 3 * MB);       // 16 MB  [2048,4096] f16
  u16*   W2f  = (u16*)  (ws + 19 * MB);      //  8 MB  [2048,2048] f16
  u16*   outb = (u16*)  (ws + 27 * MB);      // 16 MB  [4096,2048] f16
  u16*   attn = (u16*)  (ws + 43 * MB);      // 32 MB  [4096,4096] f16
  // reusable region A [75, 139 MB) — lifetimes strictly sequential:
  u16*   xh   = (u16*)  (ws + 75 * MB);      // 16 MB  (dead after qk gemm)
  u16*   xl   = (u16*)  (ws + 91 * MB);      // 16 MB  (dead after qk gemm)
  float* QKp  = (float*)(ws + 107 * MB);     // 32 MB  8 x [4096,256] partials
  float* S    = (float*)(ws + 75 * MB);      // 64 MB  scores (after xh/xl/QKp dead)
  float* P0   = (float*)(ws + 75 * MB);      // 32 MB  split-K partial 0 (after S dead)
  float* P1   = (float*)(ws + 107 * MB);     // 32 MB  split-K partial 1

  const int XN4 = NCTX * DMODEL / 4;
  const int QKN4 = NCTX * 256 / 4;

  // fused prep: x f16-split + f16 transpose + W/W2 casts
  prep_all<<<6656, 256, 0, stream>>>(x, Wq, Wk, W2, xh, xl, Wf, W2f, xT);

  // q,k = (xh+xl) @ [Wq;Wk]^T  (f16x2 2-pass), split-K KC=256 -> 512 blocks
  gemm_f16x2_p<<<dim3(NCTX / 128, 2, 8), 256, 0, stream>>>(
      xh, xl, Wf, QKp, DMODEL, DMODEL, 256, DMODEL, 256, (size_t)NCTX * 256);
  reduce8_f16<<<(QKN4 + 255) / 256, 256, 0, stream>>>(QKp, QKf, QKN4);

  // scores = q @ k^T, single-pass f16, lower-triangular tiles, direct fp32 store
  gemm_f16_p<<<dim3(NCTX / 128, NCTX / 128, 1), 256, 0, stream>>>(
      QKf, QKf + DHEAD, S, 256, 256, NCTX, DHEAD, DHEAD, 0, 0, 1);
  softmax_rows<<<NCTX, 256, 0, stream>>>(S, attn);

  // out = attn @ x (causal): z=2, KC=2048, fp32 partials
  gemm_f16_p<<<dim3(NCTX / 128, DMODEL / 128, 2), 256, 0, stream>>>(
      attn, xT, P0, NCTX, NCTX, DMODEL, NCTX, 2048, (size_t)NCTX * DMODEL, 1, 0);
  reduce2_cast<<<(XN4 + 255) / 256, 256, 0, stream>>>(P0, P1, outb, XN4,
                                                      2048 * 2048 / 4);

  // final = out @ W2^T: z=2, KC=1024, fp32 partials
  gemm_f16_p<<<dim3(NCTX / 128, DMODEL / 128, 2), 256, 0, stream>>>(
      outb, W2f, P0, DMODEL, DMODEL, DMODEL, DMODEL, 1024, (size_t)NCTX * DMODEL, 0, 0);
  reduce2_f32<<<(XN4 + 255) / 256, 256, 0, stream>>>(P0, P1, (float*)d_out, XN4);
}